// Round 3
// baseline (107.541 us; speedup 1.0000x reference)
//
#include <hip/hip_runtime.h>
#include <hip/hip_bf16.h>

#define BDIM 8192
#define DDIM 256
// 256x128 tiles: 32 row-bands x 64 col-bands, upper-triangle overlap ->
// for row band ti, col tiles tj in [2*ti, 64): count 64-2*ti, total 1056.
#define NBLK 1056
#define MARGIN1 5.0f
#define MARGIN2 10.0f
#define INV_NPAIRS (1.0f / 33550336.0f)   // 8192*8191/2

typedef __attribute__((ext_vector_type(4))) float  f32x4;
typedef __attribute__((ext_vector_type(4))) __bf16 bf16x4;
typedef __attribute__((ext_vector_type(8))) __bf16 bf16x8;

__device__ inline void gload_lds16(const void* g, void* s) {
    __builtin_amdgcn_global_load_lds(
        (const __attribute__((address_space(1))) void*)g,
        (__attribute__((address_space(3))) void*)s, 16, 0, 0);
}

// One wave per row: fp32 -> bf16 (RNE), sq from ROUNDED values (so
// d2 = |Fb_i - Fb_j|^2 is mathematically >= 0), pack {sq, label*2+method}.
__global__ __launch_bounds__(256) void prep_kernel(
    const float* __restrict__ F, const int* __restrict__ labels,
    const int* __restrict__ mlabels, __bf16* __restrict__ Fb,
    float2* __restrict__ meta)
{
    const int row  = blockIdx.x * 4 + (threadIdx.x >> 6);
    const int lane = threadIdx.x & 63;
    f32x4 v = *reinterpret_cast<const f32x4*>(F + (size_t)row * DDIM + lane * 4);
    bf16x4 b;
    b.x = (__bf16)v.x; b.y = (__bf16)v.y; b.z = (__bf16)v.z; b.w = (__bf16)v.w;
    *reinterpret_cast<bf16x4*>(Fb + (size_t)row * DDIM + lane * 4) = b;
    float f0 = (float)b.x, f1 = (float)b.y, f2 = (float)b.z, f3 = (float)b.w;
    float s = f0 * f0 + f1 * f1 + f2 * f2 + f3 * f3;
    #pragma unroll
    for (int off = 32; off > 0; off >>= 1) s += __shfl_xor(s, off, 64);
    if (lane == 0)
        meta[row] = make_float2(s, __int_as_float(labels[row] * 2 + mlabels[row]));
}

#define FT(t) ((t) * (65 - (t)))   // first linear id of 256-row band t

// 256x128 Gram tile per block, 512 threads (8 waves in 4x2, each wave a
// 64x64 subtile = 4x4 of mfma_f32_16x16x32_bf16). XOR-swizzled LDS fed by
// global_load_lds; fused distance/margin epilogue; per-element i<j mask.
__global__ __launch_bounds__(512) void pair_loss_kernel(
    const __bf16* __restrict__ Fb, const float2* __restrict__ meta,
    float* __restrict__ partial)
{
    // linear block id -> (ti: 256-row band, tj: 128-col band), tj >= 2*ti
    const int L = blockIdx.x;
    int ti = (int)((65.0f - sqrtf(4225.0f - 4.0f * (float)L)) * 0.5f);
    while (FT(ti + 1) <= L) ++ti;
    while (FT(ti) > L) --ti;
    const int tj = 2 * ti + (L - FT(ti));

    __shared__ __bf16 As[256 * 64];   // 32 KB, XOR-swizzled 16B chunks
    __shared__ __bf16 Bs[128 * 64];   // 16 KB
    __shared__ float2 metaS[384];     // [0,256) row band, [256,384) col band
    __shared__ float  red[8];

    const int tid  = threadIdx.x;
    const int lane = tid & 63;
    const int wid  = tid >> 6;        // 0..7
    const int wm   = wid >> 1;        // 0..3 (row quadrant)
    const int wn   = wid & 1;         // 0..1 (col half)
    const int quad = lane >> 4;
    const int coll = lane & 15;
    const int rowq = quad * 4;

    const int i0 = ti * 256;
    const int j0 = tj * 128;

    if (tid < 256)      metaS[tid] = meta[i0 + tid];
    else if (tid < 384) metaS[tid] = meta[j0 + tid - 256];

    f32x4 acc[4][4];
    #pragma unroll
    for (int a = 0; a < 4; a++)
        #pragma unroll
        for (int b = 0; b < 4; b++)
            acc[a][b] = (f32x4){0.f, 0.f, 0.f, 0.f};

    for (int k0 = 0; k0 < DDIM; k0 += 64) {
        // A: 2048 16B chunks (4/thread); B: 1024 (2/thread). LDS slot s holds
        // global chunk ((s&7) ^ ((s>>3)&7)) of row (s>>3) -> conflict-free.
        #pragma unroll
        for (int it = 0; it < 4; ++it) {
            const int slotbase = it * 512 + wid * 64;   // wave-uniform
            const int slot = slotbase + lane;
            const int row  = slot >> 3;                 // 0..255
            const int cg   = (slot & 7) ^ (row & 7);
            gload_lds16(Fb + (size_t)(i0 + row) * DDIM + k0 + cg * 8, &As[slotbase * 8]);
        }
        #pragma unroll
        for (int it = 0; it < 2; ++it) {
            const int slotbase = it * 512 + wid * 64;
            const int slot = slotbase + lane;
            const int row  = slot >> 3;                 // 0..127
            const int cg   = (slot & 7) ^ (row & 7);
            gload_lds16(Fb + (size_t)(j0 + row) * DDIM + k0 + cg * 8, &Bs[slotbase * 8]);
        }
        __syncthreads();

        #pragma unroll
        for (int ks = 0; ks < 2; ++ks) {
            const int ck = ks * 4 + quad;               // 16B chunk index in row
            bf16x8 af[4], bg[4];
            #pragma unroll
            for (int t = 0; t < 4; t++) {
                const int ra = wm * 64 + t * 16 + coll;
                const int rb = wn * 64 + t * 16 + coll;
                af[t] = *reinterpret_cast<const bf16x8*>(&As[ra * 64 + (ck ^ (ra & 7)) * 8]);
                bg[t] = *reinterpret_cast<const bf16x8*>(&Bs[rb * 64 + (ck ^ (rb & 7)) * 8]);
            }
            #pragma unroll
            for (int tm = 0; tm < 4; tm++)
                #pragma unroll
                for (int tn = 0; tn < 4; tn++)
                    acc[tm][tn] = __builtin_amdgcn_mfma_f32_16x16x32_bf16(
                        af[tm], bg[tn], acc[tm][tn], 0, 0, 0);
        }
        __syncthreads();
    }

    // Epilogue. C/D layout: col = lane&15, row = quad*4 + reg.
    float sj[4]; int cj[4], jv[4];
    #pragma unroll
    for (int tn = 0; tn < 4; tn++) {
        const int jl = wn * 64 + tn * 16 + coll;
        float2 mm = metaS[256 + jl];
        sj[tn] = mm.x; cj[tn] = __float_as_int(mm.y); jv[tn] = j0 + jl;
    }

    float lsum = 0.0f, dmin = 1e30f;
    #pragma unroll
    for (int tm = 0; tm < 4; tm++) {
        #pragma unroll
        for (int r = 0; r < 4; r++) {
            const int il = wm * 64 + tm * 16 + rowq + r;
            float2 mr = metaS[il];
            const float si = mr.x;
            const int   ci = __float_as_int(mr.y);
            const int   i  = i0 + il;
            #pragma unroll
            for (int tn = 0; tn < 4; tn++) {
                float d2   = fmaxf(fmaf(acc[tm][tn][r], -2.0f, si + sj[tn]), 0.0f);
                float dist = __builtin_amdgcn_sqrtf(d2);
                bool  w    = (i < jv[tn]);
                bool  same = (((ci ^ cj[tn]) >> 1) == 0);
                lsum += (w && same) ? dist : 0.0f;
                dmin  = fminf(dmin, (w && !same) ? d2 : 1e30f);
            }
        }
    }

    // Exact margin terms — only when some in-mask different-label pair has
    // d2 < MARGIN2^2 (never for ~N(0,I) data at D=256; path keeps exactness).
    if (__any(dmin < MARGIN2 * MARGIN2)) {
        #pragma unroll
        for (int tm = 0; tm < 4; tm++) {
            #pragma unroll
            for (int r = 0; r < 4; r++) {
                const int il = wm * 64 + tm * 16 + rowq + r;
                float2 mr = metaS[il];
                const float si = mr.x;
                const int   ci = __float_as_int(mr.y);
                const int   i  = i0 + il;
                #pragma unroll
                for (int tn = 0; tn < 4; tn++) {
                    int x = ci ^ cj[tn];
                    if ((x >> 1) != 0 && i < jv[tn]) {
                        float d2   = fmaxf(fmaf(acc[tm][tn][r], -2.0f, si + sj[tn]), 0.0f);
                        float dist = __builtin_amdgcn_sqrtf(d2);
                        float m    = (x & 1) ? MARGIN2 : MARGIN1;
                        lsum += fmaxf(m - dist, 0.0f);
                    }
                }
            }
        }
    }

    #pragma unroll
    for (int off = 32; off > 0; off >>= 1) lsum += __shfl_xor(lsum, off, 64);
    if (lane == 0) red[wid] = lsum;
    __syncthreads();
    if (tid == 0) {
        float s = 0.f;
        #pragma unroll
        for (int wv = 0; wv < 8; wv++) s += red[wv];
        partial[L] = s;
    }
}

__global__ __launch_bounds__(256) void reduce_kernel(
    const float* __restrict__ partial, float* __restrict__ out)
{
    __shared__ float red[4];
    float s = 0.0f;
    for (int i = threadIdx.x; i < NBLK; i += 256) s += partial[i];
    #pragma unroll
    for (int off = 32; off > 0; off >>= 1) s += __shfl_xor(s, off, 64);
    const int lane = threadIdx.x & 63, wid = threadIdx.x >> 6;
    if (lane == 0) red[wid] = s;
    __syncthreads();
    if (threadIdx.x == 0)
        out[0] = (red[0] + red[1] + red[2] + red[3]) * INV_NPAIRS;
}

extern "C" void kernel_launch(void* const* d_in, const int* in_sizes, int n_in,
                              void* d_out, int out_size, void* d_ws, size_t ws_size,
                              hipStream_t stream) {
    const float* F       = (const float*)d_in[0];
    const int*   labels  = (const int*)d_in[1];
    const int*   mlabels = (const int*)d_in[2];
    float*       out     = (float*)d_out;

    __bf16* Fb      = (__bf16*)d_ws;                                    // 4 MiB
    float2* meta    = (float2*)((char*)d_ws + (size_t)BDIM * DDIM * 2); // 64 KiB
    float*  partial = (float*)((char*)meta + (size_t)BDIM * sizeof(float2));

    prep_kernel<<<BDIM / 4, 256, 0, stream>>>(F, labels, mlabels, Fb, meta);
    pair_loss_kernel<<<NBLK, 512, 0, stream>>>(Fb, meta, partial);
    reduce_kernel<<<1, 256, 0, stream>>>(partial, out);
}

// Round 4
// 85.822 us; speedup vs baseline: 1.2531x; 1.2531x over previous
//
#include <hip/hip_runtime.h>
#include <hip/hip_bf16.h>
#include <hip/hip_fp8.h>

#define BDIM 8192
#define DDIM 256
#define NT 64                 // 8192/128 tiles per dim
#define NBLK 2080             // NT*(NT+1)/2 upper-triangle tiles
#define MARGIN1 5.0f
#define MARGIN2 10.0f
#define INV_NPAIRS (1.0f / 33550336.0f)   // 8192*8191/2

typedef __attribute__((ext_vector_type(4))) float f32x4;
typedef __attribute__((ext_vector_type(4))) int   i32x4;
typedef __attribute__((ext_vector_type(8))) int   i32x8;

__device__ inline void gload_lds16(const void* g, void* s) {
    __builtin_amdgcn_global_load_lds(
        (const __attribute__((address_space(1))) void*)g,
        (__attribute__((address_space(3))) void*)s, 16, 0, 0);
}

// One wave per row: fp32 -> fp8 e4m3 (OCP, RNE saturating), sq from the
// DEQUANTIZED values (so d2 = |Q(f_i)-Q(f_j)|^2 is mathematically >= 0),
// pack {sq, label*2+method}.
__global__ __launch_bounds__(256) void prep_kernel(
    const float* __restrict__ F, const int* __restrict__ labels,
    const int* __restrict__ mlabels, unsigned char* __restrict__ Fq,
    float2* __restrict__ meta)
{
    const int row  = blockIdx.x * 4 + (threadIdx.x >> 6);
    const int lane = threadIdx.x & 63;
    f32x4 v = *reinterpret_cast<const f32x4*>(F + (size_t)row * DDIM + lane * 4);
    __hip_fp8_e4m3 q0(v.x), q1(v.y), q2(v.z), q3(v.w);
    unsigned int packed = (unsigned int)q0.__x | ((unsigned int)q1.__x << 8)
                        | ((unsigned int)q2.__x << 16) | ((unsigned int)q3.__x << 24);
    *reinterpret_cast<unsigned int*>(Fq + (size_t)row * DDIM + lane * 4) = packed;
    float f0 = (float)q0, f1 = (float)q1, f2 = (float)q2, f3 = (float)q3;
    float s = f0 * f0 + f1 * f1 + f2 * f2 + f3 * f3;
    #pragma unroll
    for (int off = 32; off > 0; off >>= 1) s += __shfl_xor(s, off, 64);
    if (lane == 0)
        meta[row] = make_float2(s, __int_as_float(labels[row] * 2 + mlabels[row]));
}

#define FT(t) ((t) * (129 - (t)) / 2)   // first linear id of tile-row t

// 128x128 Gram tile per block, 256 threads (4 waves in 2x2, each wave a
// 64x64 subtile = 4x4 of mfma_scale_f32_16x16x128_f8f6f4 with unit scales).
// XOR-swizzled fp8 LDS fed by global_load_lds; fused epilogue.
__global__ __launch_bounds__(256, 3) void pair_loss_kernel(
    const unsigned char* __restrict__ Fq, const float2* __restrict__ meta,
    float* __restrict__ partial)
{
    // linear block id -> upper-triangle (ti, tj)
    const int L = blockIdx.x;
    int ti = (int)((129.0f - sqrtf(16641.0f - 8.0f * (float)L)) * 0.5f);
    while (FT(ti + 1) <= L) ++ti;
    while (FT(ti) > L) --ti;
    const int tj = ti + (L - FT(ti));

    __shared__ __align__(16) unsigned char As[128 * 128];  // 16 KB per K-half
    __shared__ __align__(16) unsigned char Bs[128 * 128];
    __shared__ float2 metaS[256];   // [0,128) rows, [128,256) cols
    __shared__ float  red[4];

    const int tid  = threadIdx.x;
    const int lane = tid & 63;
    const int wid  = tid >> 6;
    const int wm   = wid >> 1;      // 0..1
    const int wn   = wid & 1;       // 0..1
    const int quad = lane >> 4;
    const int coll = lane & 15;
    const int rowq = quad * 4;

    const int i0 = ti * 128;
    const int j0 = tj * 128;

    if (tid < 128) metaS[tid] = meta[i0 + tid];
    else           metaS[tid] = meta[j0 + tid - 128];

    f32x4 acc[4][4];
    #pragma unroll
    for (int a = 0; a < 4; a++)
        #pragma unroll
        for (int b = 0; b < 4; b++)
            acc[a][b] = (f32x4){0.f, 0.f, 0.f, 0.f};

    #pragma unroll
    for (int k0 = 0; k0 < DDIM; k0 += 128) {
        // Stage K-half: 1024 16B chunks per tile (4/thread). LDS slot s holds
        // global chunk ((s&7) ^ ((s>>3)&7)) of row (s>>3) -> conflict-free
        // on both the DMA write and the 32B fragment reads.
        #pragma unroll
        for (int it = 0; it < 4; ++it) {
            const int slotbase = it * 256 + wid * 64;   // wave-uniform
            const int slot = slotbase + lane;
            const int row  = slot >> 3;                 // 0..127
            const int cg   = (slot & 7) ^ (row & 7);
            gload_lds16(Fq + (size_t)(i0 + row) * DDIM + k0 + cg * 16, &As[slotbase * 16]);
            gload_lds16(Fq + (size_t)(j0 + row) * DDIM + k0 + cg * 16, &Bs[slotbase * 16]);
        }
        __syncthreads();

        // Fragments: A lane holds m = lane&15, k = quad*32 + [0,32).
        i32x8 af[4], bf[4];
        #pragma unroll
        for (int t = 0; t < 4; t++) {
            const int ra = wm * 64 + t * 16 + coll;
            const int c0 = (2 * quad) ^ (ra & 7);
            const int c1 = (2 * quad + 1) ^ (ra & 7);
            i32x4 lo = *reinterpret_cast<const i32x4*>(&As[ra * 128 + c0 * 16]);
            i32x4 hi = *reinterpret_cast<const i32x4*>(&As[ra * 128 + c1 * 16]);
            af[t] = (i32x8){lo.x, lo.y, lo.z, lo.w, hi.x, hi.y, hi.z, hi.w};
        }
        #pragma unroll
        for (int t = 0; t < 4; t++) {
            const int rb = wn * 64 + t * 16 + coll;
            const int c0 = (2 * quad) ^ (rb & 7);
            const int c1 = (2 * quad + 1) ^ (rb & 7);
            i32x4 lo = *reinterpret_cast<const i32x4*>(&Bs[rb * 128 + c0 * 16]);
            i32x4 hi = *reinterpret_cast<const i32x4*>(&Bs[rb * 128 + c1 * 16]);
            bf[t] = (i32x8){lo.x, lo.y, lo.z, lo.w, hi.x, hi.y, hi.z, hi.w};
        }

        #pragma unroll
        for (int tm = 0; tm < 4; tm++)
            #pragma unroll
            for (int tn = 0; tn < 4; tn++)
                acc[tm][tn] = __builtin_amdgcn_mfma_scale_f32_16x16x128_f8f6f4(
                    af[tm], bf[tn], acc[tm][tn],
                    0 /*A fmt: fp8 e4m3*/, 0 /*B fmt*/,
                    0, 127 /*scale A = 2^0*/, 0, 127 /*scale B = 2^0*/);
        __syncthreads();
    }

    // Epilogue. C/D layout: col = lane&15, row = quad*4 + reg.
    float sj[4]; int cj[4];
    #pragma unroll
    for (int tn = 0; tn < 4; tn++) {
        float2 mm = metaS[128 + wn * 64 + tn * 16 + coll];
        sj[tn] = mm.x; cj[tn] = __float_as_int(mm.y);
    }

    float lsum = 0.0f, dmin = 1e30f;
    if (ti != tj) {
        // Fast path: every element has i < j.
        #pragma unroll
        for (int tm = 0; tm < 4; tm++) {
            #pragma unroll
            for (int r = 0; r < 4; r++) {
                float2 mr = metaS[wm * 64 + tm * 16 + rowq + r];
                const float si = mr.x;
                const int   ci = __float_as_int(mr.y);
                #pragma unroll
                for (int tn = 0; tn < 4; tn++) {
                    float d2   = fmaxf(fmaf(acc[tm][tn][r], -2.0f, si + sj[tn]), 0.0f);
                    float dist = __builtin_amdgcn_sqrtf(d2);
                    bool  same = (((unsigned)(ci ^ cj[tn])) < 2u);
                    lsum += same ? dist : 0.0f;
                    dmin  = fminf(dmin, same ? 1e30f : d2);
                }
            }
        }
    } else {
        // Diagonal tile: per-element i<j mask.
        #pragma unroll
        for (int tm = 0; tm < 4; tm++) {
            #pragma unroll
            for (int r = 0; r < 4; r++) {
                const int il = wm * 64 + tm * 16 + rowq + r;
                float2 mr = metaS[il];
                const float si = mr.x;
                const int   ci = __float_as_int(mr.y);
                #pragma unroll
                for (int tn = 0; tn < 4; tn++) {
                    const int jl = wn * 64 + tn * 16 + coll;
                    bool  w    = (il < jl);
                    float d2   = fmaxf(fmaf(acc[tm][tn][r], -2.0f, si + sj[tn]), 0.0f);
                    float dist = __builtin_amdgcn_sqrtf(d2);
                    bool  same = (((unsigned)(ci ^ cj[tn])) < 2u);
                    lsum += (w && same) ? dist : 0.0f;
                    dmin  = fminf(dmin, (w && !same) ? d2 : 1e30f);
                }
            }
        }
    }

    // Exact margin terms — only when some in-mask different-label pair has
    // d2 < MARGIN2^2 (never fires for this data; keeps kernel exact).
    if (__any(dmin < MARGIN2 * MARGIN2)) {
        #pragma unroll
        for (int tm = 0; tm < 4; tm++) {
            #pragma unroll
            for (int r = 0; r < 4; r++) {
                const int il = wm * 64 + tm * 16 + rowq + r;
                float2 mr = metaS[il];
                const float si = mr.x;
                const int   ci = __float_as_int(mr.y);
                const int   i  = i0 + il;
                #pragma unroll
                for (int tn = 0; tn < 4; tn++) {
                    const int jl = wn * 64 + tn * 16 + coll;
                    int x = ci ^ cj[tn];
                    if ((x >> 1) != 0 && i < j0 + jl) {
                        float d2   = fmaxf(fmaf(acc[tm][tn][r], -2.0f, si + sj[tn]), 0.0f);
                        float dist = __builtin_amdgcn_sqrtf(d2);
                        float m    = (x & 1) ? MARGIN2 : MARGIN1;
                        lsum += fmaxf(m - dist, 0.0f);
                    }
                }
            }
        }
    }

    #pragma unroll
    for (int off = 32; off > 0; off >>= 1) lsum += __shfl_xor(lsum, off, 64);
    if (lane == 0) red[wid] = lsum;
    __syncthreads();
    if (tid == 0) partial[L] = red[0] + red[1] + red[2] + red[3];
}

__global__ __launch_bounds__(256) void reduce_kernel(
    const float* __restrict__ partial, float* __restrict__ out)
{
    __shared__ float red[4];
    float s = 0.0f;
    for (int i = threadIdx.x; i < NBLK; i += 256) s += partial[i];
    #pragma unroll
    for (int off = 32; off > 0; off >>= 1) s += __shfl_xor(s, off, 64);
    const int lane = threadIdx.x & 63, wid = threadIdx.x >> 6;
    if (lane == 0) red[wid] = s;
    __syncthreads();
    if (threadIdx.x == 0)
        out[0] = (red[0] + red[1] + red[2] + red[3]) * INV_NPAIRS;
}

extern "C" void kernel_launch(void* const* d_in, const int* in_sizes, int n_in,
                              void* d_out, int out_size, void* d_ws, size_t ws_size,
                              hipStream_t stream) {
    const float* F       = (const float*)d_in[0];
    const int*   labels  = (const int*)d_in[1];
    const int*   mlabels = (const int*)d_in[2];
    float*       out     = (float*)d_out;

    unsigned char* Fq      = (unsigned char*)d_ws;                        // 2 MiB
    float2*        meta    = (float2*)((char*)d_ws + (size_t)BDIM * DDIM); // 64 KiB
    float*         partial = (float*)((char*)meta + (size_t)BDIM * sizeof(float2));

    prep_kernel<<<BDIM / 4, 256, 0, stream>>>(F, labels, mlabels, Fq, meta);
    pair_loss_kernel<<<NBLK, 256, 0, stream>>>(Fq, meta, partial);
    reduce_kernel<<<1, 256, 0, stream>>>(partial, out);
}